// Round 3
// baseline (554.547 us; speedup 1.0000x reference)
//
#include <hip/hip_runtime.h>
#include <hip/hip_bf16.h>
#include <math.h>

// Problem constants
#define N_DEST 16000   // B * D_CNT
#define KN     32      // neighbors per dest
#define HIDN   128
#define NH     4
#define HD     32
#define SRCD   64
#define EDGED  16
#define XD     80      // SRCD + EDGED
#define XDP    96      // XD padded to 3 K-tiles of 32
#define SXP    104     // sx LDS row stride (96 + 8)
#define SNP    136     // s_sin LDS row stride (128 + 8)
#define G      2       // dest nodes per block

typedef __attribute__((ext_vector_type(8))) short frag8;   // 8 bf16 (4 VGPR)
typedef __attribute__((ext_vector_type(4))) float f32x4;

// fast exact-erf GELU (A&S 7.1.26, |erf err| <= 1.5e-7)
__device__ __forceinline__ float gelu_fast(float x) {
    float y  = x * 0.70710678118654752440f;
    float ay = fabsf(y);
    float t  = 1.0f / (1.0f + 0.3275911f * ay);
    float p  = 1.061405429f;
    p = fmaf(p, t, -1.453152027f);
    p = fmaf(p, t,  1.421413741f);
    p = fmaf(p, t, -0.284496736f);
    p = fmaf(p, t,  0.254829592f);
    float er = 1.0f - p * t * __expf(-ay * ay);
    er = copysignf(er, y);
    return 0.5f * x * (1.0f + er);
}
__device__ __forceinline__ unsigned short f2bf(float f) {
    __hip_bfloat16 h = __float2bfloat16(f);
    union { __hip_bfloat16 h; unsigned short u; } c; c.h = h; return c.u;
}
__device__ __forceinline__ unsigned int pk2bf(float x, float y) {
    __hip_bfloat162 h2 = __float22bfloat162_rn(make_float2(x, y));
    union { __hip_bfloat162 h; unsigned int u; } c; c.h = h2; return c.u;
}

// ---- prep: convert W_src (pad K 80->96) and Wqkv K/V rows to bf16 in d_ws ----
__global__ void prep_weights(const float* __restrict__ W_src,
                             const float* __restrict__ Wqkv,
                             unsigned short* __restrict__ ws) {
    int i = blockIdx.x * 256 + threadIdx.x;
    if (i < 128 * XDP) {
        int r = i / XDP, c = i - r * XDP;
        ws[i] = f2bf(c < XD ? W_src[r * XD + c] : 0.0f);
    } else {
        int j = i - 128 * XDP;           // < 256*128
        int r = j >> 7, c = j & 127;
        ws[i] = f2bf(Wqkv[(128 + r) * HIDN + c]);
    }
}

__global__ __launch_bounds__(256, 4) void fused_gat_mfma(
    const float* __restrict__ src,    // (16000, 64)
    const float* __restrict__ dest,   // (16000, 64)
    const int*   __restrict__ adj,    // (32, 16000)
    const int*   __restrict__ mask,   // (16000, 32)
    const float* __restrict__ edges,  // (32, 16000, 16)
    const float* __restrict__ b_src,  // (128)
    const float* __restrict__ W_dest, // (128, 64)
    const float* __restrict__ b_dest, // (128)
    const float* __restrict__ Wqkv,   // (384, 128) fp32 (Q rows used here)
    const float* __restrict__ bqkv,   // (384)
    const float* __restrict__ Wo,     // (128, 128)
    const float* __restrict__ bo,     // (128)
    const float* __restrict__ ln_g,
    const float* __restrict__ ln_b,
    const unsigned short* __restrict__ Wsb,   // bf16 128 x 96
    const unsigned short* __restrict__ Wkvb,  // bf16 256 x 128 (K rows 0-127, V 128-255)
    float* __restrict__ out)
{
    const int tid  = threadIdx.x;
    const int n0   = blockIdx.x * G;
    const int w    = tid >> 6;        // wave id 0..3
    const int lane = tid & 63;
    const int lg   = lane >> 4;       // 0..3
    const int lm   = lane & 15;       // 0..15

    __shared__ __align__(16) unsigned short sx[G * KN][SXP];      // 13.0 KB
    __shared__ __align__(16) unsigned short s_sin[G * KN][SNP];   // 17.0 KB
    __shared__ __align__(16) float s_dest[G][HIDN];
    __shared__ __align__(16) float s_q[G][HIDN];
    __shared__ __align__(16) float s_attn[G][NH][KN];
    __shared__ __align__(16) float s_ctx[G][HIDN];
    __shared__ float s_red[4][2];

    // ---------------- phase 0: gather x rows (bf16, packed stores) + dest_in ----
    {
        const int row = tid >> 2;            // 0..63  (g*32 + kk)
        const int part = tid & 3;
        const int g = row >> 5, kk = row & 31;
        const int n = n0 + g;
        const int a = adj[kk * N_DEST + n];
        const float* srow = (a == 0) ? nullptr : src + (size_t)(a - 1) * SRCD;
        if (part < 3) {
            const int c0 = part * 20;        // cols [c0, c0+20), pure src
            #pragma unroll
            for (int q = 0; q < 5; ++q) {
                float4 f = srow ? *(const float4*)(srow + c0 + q * 4)
                                : make_float4(0.f, 0.f, 0.f, 0.f);
                *(unsigned int*)&sx[row][c0 + q * 4]     = pk2bf(f.x, f.y);
                *(unsigned int*)&sx[row][c0 + q * 4 + 2] = pk2bf(f.z, f.w);
            }
        } else {
            float4 f = srow ? *(const float4*)(srow + 60)
                            : make_float4(0.f, 0.f, 0.f, 0.f);
            *(unsigned int*)&sx[row][60] = pk2bf(f.x, f.y);
            *(unsigned int*)&sx[row][62] = pk2bf(f.z, f.w);
            const float4* ep = (const float4*)(edges + ((size_t)kk * N_DEST + n) * EDGED);
            #pragma unroll
            for (int q = 0; q < 4; ++q) {
                float4 e = ep[q];
                *(unsigned int*)&sx[row][64 + q * 4]     = pk2bf(e.x, e.y);
                *(unsigned int*)&sx[row][64 + q * 4 + 2] = pk2bf(e.z, e.w);
            }
            #pragma unroll
            for (int c = 80; c < XDP; c += 2) *(unsigned int*)&sx[row][c] = 0u;
        }
    }
    {
        const int g = tid >> 7, j = tid & 127;
        float acc = b_dest[j];
        const float4* w4 = (const float4*)(W_dest + j * SRCD);
        const float4* x4 = (const float4*)(dest + (size_t)(n0 + g) * SRCD);
        #pragma unroll
        for (int c = 0; c < SRCD / 4; ++c) {
            float4 wv = w4[c]; float4 x = x4[c];
            acc = fmaf(wv.x, x.x, acc); acc = fmaf(wv.y, x.y, acc);
            acc = fmaf(wv.z, x.z, acc); acc = fmaf(wv.w, x.w, acc);
        }
        s_dest[g][j] = gelu_fast(acc);
    }
    __syncthreads();

    // ---------------- phase 1: q projection + GEMM-D -> gelu -> s_sin ----------
    {
        const int g = tid >> 7, j = tid & 127;
        float acc = bqkv[j];
        const float4* w4 = (const float4*)(Wqkv + (size_t)j * HIDN);
        const float4* x4 = (const float4*)s_dest[g];
        #pragma unroll
        for (int c = 0; c < HIDN / 4; ++c) {
            float4 wv = w4[c]; float4 x = x4[c];
            acc = fmaf(wv.x, x.x, acc); acc = fmaf(wv.y, x.y, acc);
            acc = fmaf(wv.z, x.z, acc); acc = fmaf(wv.w, x.w, acc);
        }
        s_q[g][j] = acc * 0.17677669529663688110f;   // 1/sqrt(32)
    }
    {
        const int row0 = (w >> 1) * 32, col0 = (w & 1) * 64;
        f32x4 acc[2][4];
        #pragma unroll
        for (int c = 0; c < 4; ++c) {
            float bias = b_src[col0 + c * 16 + lm];
            #pragma unroll
            for (int r = 0; r < 2; ++r) acc[r][c] = (f32x4){bias, bias, bias, bias};
        }
        #pragma unroll
        for (int kt = 0; kt < 3; ++kt) {
            frag8 a[2], b[4];
            #pragma unroll
            for (int r = 0; r < 2; ++r)
                a[r] = *(const frag8*)&sx[row0 + r * 16 + lm][kt * 32 + lg * 8];
            #pragma unroll
            for (int c = 0; c < 4; ++c)
                b[c] = *(const frag8*)(Wsb + (size_t)(col0 + c * 16 + lm) * XDP + kt * 32 + lg * 8);
            #pragma unroll
            for (int r = 0; r < 2; ++r)
                #pragma unroll
                for (int c = 0; c < 4; ++c)
                    acc[r][c] = __builtin_amdgcn_mfma_f32_16x16x32_bf16(a[r], b[c], acc[r][c], 0, 0, 0);
        }
        #pragma unroll
        for (int r = 0; r < 2; ++r)
            #pragma unroll
            for (int c = 0; c < 4; ++c)
                #pragma unroll
                for (int e = 0; e < 4; ++e)
                    s_sin[row0 + r * 16 + lg * 4 + e][col0 + c * 16 + lm] =
                        f2bf(gelu_fast(acc[r][c][e]));
    }
    __syncthreads();

    // ---------------- phase 2: GEMM-E (K | V) + in-register scores ------------
    // wave 0,1 -> K feature cols [w*64, w*64+64); wave 2,3 -> V cols [(w-2)*64, ...)
    f32x4 acc[4][4];
    {
        const int col0 = w * 64;
        #pragma unroll
        for (int c = 0; c < 4; ++c) {
            float bias = bqkv[128 + col0 + c * 16 + lm];
            #pragma unroll
            for (int r = 0; r < 4; ++r) acc[r][c] = (f32x4){bias, bias, bias, bias};
        }
        #pragma unroll
        for (int kt = 0; kt < 4; ++kt) {
            frag8 a[4], b[4];
            #pragma unroll
            for (int r = 0; r < 4; ++r)
                a[r] = *(const frag8*)&s_sin[r * 16 + lm][kt * 32 + lg * 8];
            #pragma unroll
            for (int c = 0; c < 4; ++c)
                b[c] = *(const frag8*)(Wkvb + (size_t)(col0 + c * 16 + lm) * HIDN + kt * 32 + lg * 8);
            #pragma unroll
            for (int r = 0; r < 4; ++r)
                #pragma unroll
                for (int c = 0; c < 4; ++c)
                    acc[r][c] = __builtin_amdgcn_mfma_f32_16x16x32_bf16(a[r], b[c], acc[r][c], 0, 0, 0);
        }
    }
    if (w < 2) {
        // scores[g][h][kk] from K accumulators: reduce over lm (16 lanes) x c-pair
        const int hbase = w * 2;
        float qv[2][4];
        #pragma unroll
        for (int g2 = 0; g2 < 2; ++g2)
            #pragma unroll
            for (int c = 0; c < 4; ++c)
                qv[g2][c] = s_q[g2][w * 64 + c * 16 + lm];
        #pragma unroll
        for (int r = 0; r < 4; ++r) {
            const int g2 = r >> 1;
            const int kk0 = (r & 1) * 16 + lg * 4;
            #pragma unroll
            for (int hp = 0; hp < 2; ++hp) {
                float sc[4];
                #pragma unroll
                for (int e = 0; e < 4; ++e)
                    sc[e] = acc[r][2 * hp][e] * qv[g2][2 * hp]
                          + acc[r][2 * hp + 1][e] * qv[g2][2 * hp + 1];
                #pragma unroll
                for (int e = 0; e < 4; ++e) {
                    float v = sc[e];
                    v += __shfl_xor(v, 1); v += __shfl_xor(v, 2);
                    v += __shfl_xor(v, 4); v += __shfl_xor(v, 8);
                    sc[e] = v;
                }
                if (lm == 0) {
                    #pragma unroll
                    for (int e = 0; e < 4; ++e)
                        s_attn[g2][hbase + hp][kk0 + e] = sc[e];
                }
            }
        }
    }
    __syncthreads();

    // ---------------- phase 3: masked softmax (in s_attn) ----------------------
    {
        const int g = tid >> 7, h = (tid >> 5) & 3, kk = tid & 31;
        float sc = s_attn[g][h][kk];
        if (mask[(n0 + g) * KN + kk] != 0) sc = -1e30f;
        float mx = sc;
        #pragma unroll
        for (int off = 16; off; off >>= 1) mx = fmaxf(mx, __shfl_xor(mx, off, 32));
        float e = __expf(sc - mx);
        float den = e;
        #pragma unroll
        for (int off = 16; off; off >>= 1) den += __shfl_xor(den, off, 32);
        s_attn[g][h][kk] = e / den;
    }
    __syncthreads();

    // ---------------- phase 4: ctx from V accumulators -------------------------
    if (w >= 2) {
        const int hbase = (w - 2) * 2;
        float4 at[2][2][2];
        #pragma unroll
        for (int g2 = 0; g2 < 2; ++g2)
            #pragma unroll
            for (int hp = 0; hp < 2; ++hp)
                #pragma unroll
                for (int rh = 0; rh < 2; ++rh)
                    at[g2][hp][rh] = *(const float4*)&s_attn[g2][hbase + hp][rh * 16 + lg * 4];
        #pragma unroll
        for (int g2 = 0; g2 < 2; ++g2) {
            #pragma unroll
            for (int c = 0; c < 4; ++c) {
                const int hp = c >> 1;
                float v = 0.0f;
                #pragma unroll
                for (int rh = 0; rh < 2; ++rh) {
                    const int r = g2 * 2 + rh;
                    float4 a = at[g2][hp][rh];
                    v = fmaf(acc[r][c][0], a.x, v); v = fmaf(acc[r][c][1], a.y, v);
                    v = fmaf(acc[r][c][2], a.z, v); v = fmaf(acc[r][c][3], a.w, v);
                }
                v += __shfl_xor(v, 16); v += __shfl_xor(v, 32);
                if (lg == 0) s_ctx[g2][(w - 2) * 64 + c * 16 + lm] = v;
            }
        }
    }
    __syncthreads();

    // ---------------- phase 5: out projection, x2, layernorm (in-reg) ----------
    {
        const int g = tid >> 7, j = tid & 127;
        float acc2 = bo[j];
        const float4* w4 = (const float4*)(Wo + (size_t)j * HIDN);
        const float4* x4 = (const float4*)s_ctx[g];
        #pragma unroll
        for (int c = 0; c < HIDN / 4; ++c) {
            float4 wv = w4[c]; float4 x = x4[c];
            acc2 = fmaf(wv.x, x.x, acc2); acc2 = fmaf(wv.y, x.y, acc2);
            acc2 = fmaf(wv.z, x.z, acc2); acc2 = fmaf(wv.w, x.w, acc2);
        }
        float o = acc2 * 2.0f;
        float s = o, ss = o * o;
        #pragma unroll
        for (int off = 32; off; off >>= 1) {
            s  += __shfl_xor(s, off);
            ss += __shfl_xor(ss, off);
        }
        if (lane == 0) { s_red[w][0] = s; s_red[w][1] = ss; }
        __syncthreads();
        float fs  = s_red[g * 2][0] + s_red[g * 2 + 1][0];
        float fss = s_red[g * 2][1] + s_red[g * 2 + 1][1];
        float mu  = fs * (1.0f / HIDN);
        float var = fss * (1.0f / HIDN) - mu * mu;
        float y = (o - mu) * rsqrtf(var + 1e-5f) * ln_g[j] + ln_b[j];
        out[(size_t)(n0 + g) * HIDN + j] = y;
    }
}

extern "C" void kernel_launch(void* const* d_in, const int* in_sizes, int n_in,
                              void* d_out, int out_size, void* d_ws, size_t ws_size,
                              hipStream_t stream) {
    const float* src    = (const float*)d_in[0];
    const float* dest   = (const float*)d_in[1];
    const int*   adj    = (const int*)  d_in[2];
    const int*   mask   = (const int*)  d_in[3];
    const float* edges  = (const float*)d_in[4];
    const float* W_src  = (const float*)d_in[5];
    const float* b_src  = (const float*)d_in[6];
    const float* W_dest = (const float*)d_in[7];
    const float* b_dest = (const float*)d_in[8];
    const float* Wqkv   = (const float*)d_in[9];
    const float* bqkv   = (const float*)d_in[10];
    const float* Wo     = (const float*)d_in[11];
    const float* bo     = (const float*)d_in[12];
    const float* ln_g   = (const float*)d_in[13];
    const float* ln_b   = (const float*)d_in[14];
    float* outp = (float*)d_out;

    unsigned short* ws = (unsigned short*)d_ws;
    const int prep_elems = 128 * XDP + 256 * HIDN;           // 45056
    prep_weights<<<prep_elems / 256, 256, 0, stream>>>(W_src, Wqkv, ws);

    fused_gat_mfma<<<N_DEST / G, 256, 0, stream>>>(
        src, dest, adj, mask, edges, b_src, W_dest, b_dest,
        Wqkv, bqkv, Wo, bo, ln_g, ln_b,
        ws, ws + 128 * XDP, outp);
}

// Round 4
// 520.767 us; speedup vs baseline: 1.0649x; 1.0649x over previous
//
#include <hip/hip_runtime.h>
#include <hip/hip_bf16.h>
#include <math.h>

// Problem constants
#define N_DEST 16000   // B * D_CNT
#define KN     32      // neighbors per dest
#define HIDN   128
#define NH     4
#define HD     32
#define SRCD   64
#define EDGED  16
#define XD     80      // SRCD + EDGED
#define XDP    96      // XD padded to 3 K-tiles of 32
#define SXP    104     // sx LDS row stride (96 + 8)
#define SNP    136     // 128-wide LDS row stride (128 + 8)
#define G      2       // dest nodes per block

typedef __attribute__((ext_vector_type(8))) short frag8;   // 8 bf16 (4 VGPR)
typedef __attribute__((ext_vector_type(4))) float f32x4;

// tanh-form GELU (|diff vs exact erf-gelu| <= ~2e-3), ~7 VALU ops
__device__ __forceinline__ float gelu_tanh(float x) {
    float t = x * x;
    float m = fmaf(t, -0.07135481627f, -1.5957691216f);   // -(2u)/x
    float e = __expf(x * m);                              // e^{-2u}
    return __fdividef(x, 1.0f + e);                       // x * sigmoid(2u)
}
__device__ __forceinline__ unsigned short f2bf(float f) {
    __hip_bfloat16 h = __float2bfloat16(f);
    union { __hip_bfloat16 h; unsigned short u; } c; c.h = h; return c.u;
}
__device__ __forceinline__ unsigned int pk2bf(float x, float y) {
    __hip_bfloat162 h2 = __float22bfloat162_rn(make_float2(x, y));
    union { __hip_bfloat162 h; unsigned int u; } c; c.h = h2; return c.u;
}
__device__ __forceinline__ float bf2f(unsigned short h) {
    union { unsigned int u; float f; } c; c.u = ((unsigned int)h) << 16;
    return c.f;
}

// ---- prep: convert W_src (pad K 80->96) and Wqkv K/V rows to bf16 in d_ws ----
__global__ void prep_weights(const float* __restrict__ W_src,
                             const float* __restrict__ Wqkv,
                             unsigned short* __restrict__ ws) {
    int i = blockIdx.x * 256 + threadIdx.x;
    if (i < 128 * XDP) {
        int r = i / XDP, c = i - r * XDP;
        ws[i] = f2bf(c < XD ? W_src[r * XD + c] : 0.0f);
    } else {
        int j = i - 128 * XDP;           // < 256*128
        int r = j >> 7, c = j & 127;
        ws[i] = f2bf(Wqkv[(128 + r) * HIDN + c]);
    }
}

__global__ __launch_bounds__(256, 4) void fused_gat_mfma(
    const float* __restrict__ src,    // (16000, 64)
    const float* __restrict__ dest,   // (16000, 64)
    const int*   __restrict__ adj,    // (32, 16000)
    const int*   __restrict__ mask,   // (16000, 32)
    const float* __restrict__ edges,  // (32, 16000, 16)
    const float* __restrict__ b_src,  // (128)
    const float* __restrict__ W_dest, // (128, 64)
    const float* __restrict__ b_dest, // (128)
    const float* __restrict__ Wqkv,   // (384, 128) fp32 (Q rows used here)
    const float* __restrict__ bqkv,   // (384)
    const float* __restrict__ Wo,     // (128, 128)
    const float* __restrict__ bo,     // (128)
    const float* __restrict__ ln_g,
    const float* __restrict__ ln_b,
    const unsigned short* __restrict__ Wsb,   // bf16 128 x 96
    const unsigned short* __restrict__ Wkvb,  // bf16 256 x 128 (K rows 0-127, V 128-255)
    float* __restrict__ out)
{
    const int tid  = threadIdx.x;
    const int n0   = blockIdx.x * G;
    const int w    = tid >> 6;        // wave id 0..3
    const int lane = tid & 63;
    const int lg   = lane >> 4;       // 0..3
    const int lm   = lane & 15;       // 0..15

    // sx dead after GEMM-D; V written in GEMM-E phase -> alias them.
    __shared__ __align__(16) union {
        unsigned short sx[G * KN][SXP];     // 13.0 KB
        unsigned short v [G * KN][SNP];     // 17.0 KB
    } u;
    __shared__ __align__(16) unsigned short s_sin[G * KN][SNP];   // 17.0 KB
    __shared__ __align__(16) float s_dest[G][HIDN];
    __shared__ __align__(16) float s_q[G][HIDN];
    __shared__ __align__(16) float s_attn[G][NH][KN];
    __shared__ __align__(16) float s_ctx[G][HIDN];
    __shared__ float s_red[4][2];

    // hoisted latency-critical loads
    const int g_row  = (tid >> 2) >> 5;            // gather row group
    const int kk_row = (tid >> 2) & 31;
    const int a_adj  = adj[kk_row * N_DEST + (n0 + g_row)];
    const int mval   = mask[(n0 + (tid >> 7)) * KN + (tid & 31)];

    // ---------------- phase 0: gather x rows (bf16) + dest_in -----------------
    {
        const int row = tid >> 2;            // 0..63  (g*32 + kk)
        const int part = tid & 3;
        const float* srow = (a_adj == 0) ? nullptr : src + (size_t)(a_adj - 1) * SRCD;
        if (part < 3) {
            const int c0 = part * 20;        // cols [c0, c0+20), pure src
            #pragma unroll
            for (int q = 0; q < 5; ++q) {
                float4 f = srow ? *(const float4*)(srow + c0 + q * 4)
                                : make_float4(0.f, 0.f, 0.f, 0.f);
                *(unsigned int*)&u.sx[row][c0 + q * 4]     = pk2bf(f.x, f.y);
                *(unsigned int*)&u.sx[row][c0 + q * 4 + 2] = pk2bf(f.z, f.w);
            }
        } else {
            float4 f = srow ? *(const float4*)(srow + 60)
                            : make_float4(0.f, 0.f, 0.f, 0.f);
            *(unsigned int*)&u.sx[row][60] = pk2bf(f.x, f.y);
            *(unsigned int*)&u.sx[row][62] = pk2bf(f.z, f.w);
            const float4* ep = (const float4*)(edges + ((size_t)kk_row * N_DEST + (n0 + g_row)) * EDGED);
            #pragma unroll
            for (int q = 0; q < 4; ++q) {
                float4 e = ep[q];
                *(unsigned int*)&u.sx[row][64 + q * 4]     = pk2bf(e.x, e.y);
                *(unsigned int*)&u.sx[row][64 + q * 4 + 2] = pk2bf(e.z, e.w);
            }
            #pragma unroll
            for (int c = 80; c < XDP; c += 2) *(unsigned int*)&u.sx[row][c] = 0u;
        }
    }
    {
        const int g = tid >> 7, j = tid & 127;
        float acc = b_dest[j];
        const float4* w4 = (const float4*)(W_dest + j * SRCD);
        const float4* x4 = (const float4*)(dest + (size_t)(n0 + g) * SRCD);
        #pragma unroll
        for (int c = 0; c < SRCD / 4; ++c) {
            float4 wv = w4[c]; float4 x = x4[c];
            acc = fmaf(wv.x, x.x, acc); acc = fmaf(wv.y, x.y, acc);
            acc = fmaf(wv.z, x.z, acc); acc = fmaf(wv.w, x.w, acc);
        }
        s_dest[g][j] = gelu_tanh(acc);
    }
    __syncthreads();

    // ---------------- phase 1: q projection + GEMM-D -> gelu -> s_sin ----------
    {
        const int g = tid >> 7, j = tid & 127;
        float acc = bqkv[j];
        const float4* w4 = (const float4*)(Wqkv + (size_t)j * HIDN);
        const float4* x4 = (const float4*)s_dest[g];
        #pragma unroll
        for (int c = 0; c < HIDN / 4; ++c) {
            float4 wv = w4[c]; float4 x = x4[c];
            acc = fmaf(wv.x, x.x, acc); acc = fmaf(wv.y, x.y, acc);
            acc = fmaf(wv.z, x.z, acc); acc = fmaf(wv.w, x.w, acc);
        }
        s_q[g][j] = acc * 0.17677669529663688110f;   // 1/sqrt(32)
    }
    {
        const int row0 = (w >> 1) * 32, col0 = (w & 1) * 64;
        f32x4 acc[2][4];
        #pragma unroll
        for (int c = 0; c < 4; ++c) {
            float bias = b_src[col0 + c * 16 + lm];
            #pragma unroll
            for (int r = 0; r < 2; ++r) acc[r][c] = (f32x4){bias, bias, bias, bias};
        }
        #pragma unroll
        for (int kt = 0; kt < 3; ++kt) {
            frag8 a[2], b[4];
            #pragma unroll
            for (int r = 0; r < 2; ++r)
                a[r] = *(const frag8*)&u.sx[row0 + r * 16 + lm][kt * 32 + lg * 8];
            #pragma unroll
            for (int c = 0; c < 4; ++c)
                b[c] = *(const frag8*)(Wsb + (size_t)(col0 + c * 16 + lm) * XDP + kt * 32 + lg * 8);
            #pragma unroll
            for (int r = 0; r < 2; ++r)
                #pragma unroll
                for (int c = 0; c < 4; ++c)
                    acc[r][c] = __builtin_amdgcn_mfma_f32_16x16x32_bf16(a[r], b[c], acc[r][c], 0, 0, 0);
        }
        #pragma unroll
        for (int r = 0; r < 2; ++r)
            #pragma unroll
            for (int c = 0; c < 4; ++c)
                #pragma unroll
                for (int e = 0; e < 4; ++e)
                    s_sin[row0 + r * 16 + lg * 4 + e][col0 + c * 16 + lm] =
                        f2bf(gelu_tanh(acc[r][c][e]));
    }
    __syncthreads();

    // ---------------- phase 2: GEMM-E (K | V) ---------------------------------
    // waves 0,1: K feature cols [w*64, w*64+64) -> in-register scores -> s_attn
    // waves 2,3: V feature cols [(w-2)*64, ...) -> bf16 -> u.v (acc dies here)
    {
        const int col0 = w * 64;                 // row offset into Wkvb (K rows 0-127, V 128-255)
        f32x4 acc[4][4];
        #pragma unroll
        for (int c = 0; c < 4; ++c) {
            float bias = bqkv[128 + col0 + c * 16 + lm];
            #pragma unroll
            for (int r = 0; r < 4; ++r) acc[r][c] = (f32x4){bias, bias, bias, bias};
        }
        #pragma unroll
        for (int kt = 0; kt < 4; ++kt) {
            frag8 a[4], b[4];
            #pragma unroll
            for (int r = 0; r < 4; ++r)
                a[r] = *(const frag8*)&s_sin[r * 16 + lm][kt * 32 + lg * 8];
            #pragma unroll
            for (int c = 0; c < 4; ++c)
                b[c] = *(const frag8*)(Wkvb + (size_t)(col0 + c * 16 + lm) * HIDN + kt * 32 + lg * 8);
            #pragma unroll
            for (int r = 0; r < 4; ++r)
                #pragma unroll
                for (int c = 0; c < 4; ++c)
                    acc[r][c] = __builtin_amdgcn_mfma_f32_16x16x32_bf16(a[r], b[c], acc[r][c], 0, 0, 0);
        }
        if (w < 2) {
            // scores from K accumulators: per head, reduce feature dim over c-pair x lm
            const int hbase = w * 2;
            float qv[2][4];
            #pragma unroll
            for (int g2 = 0; g2 < 2; ++g2)
                #pragma unroll
                for (int c = 0; c < 4; ++c)
                    qv[g2][c] = s_q[g2][w * 64 + c * 16 + lm];
            #pragma unroll
            for (int r = 0; r < 4; ++r) {
                const int g2 = r >> 1;
                const int kk0 = (r & 1) * 16 + lg * 4;
                #pragma unroll
                for (int hp = 0; hp < 2; ++hp) {
                    float sc[4];
                    #pragma unroll
                    for (int e = 0; e < 4; ++e)
                        sc[e] = acc[r][2 * hp][e] * qv[g2][2 * hp]
                              + acc[r][2 * hp + 1][e] * qv[g2][2 * hp + 1];
                    #pragma unroll
                    for (int e = 0; e < 4; ++e) {
                        float v = sc[e];
                        v += __shfl_xor(v, 1); v += __shfl_xor(v, 2);
                        v += __shfl_xor(v, 4); v += __shfl_xor(v, 8);
                        sc[e] = v;
                    }
                    if (lm == 0) {
                        #pragma unroll
                        for (int e = 0; e < 4; ++e)
                            s_attn[g2][hbase + hp][kk0 + e] = sc[e];
                    }
                }
            }
        } else {
            const int cb = (w - 2) * 64;
            #pragma unroll
            for (int r = 0; r < 4; ++r)
                #pragma unroll
                for (int c = 0; c < 4; ++c)
                    #pragma unroll
                    for (int e = 0; e < 4; ++e)
                        u.v[r * 16 + lg * 4 + e][cb + c * 16 + lm] = f2bf(acc[r][c][e]);
        }
    }
    __syncthreads();

    // ---------------- phase 3: masked softmax ---------------------------------
    {
        const int g = tid >> 7, h = (tid >> 5) & 3, kk = tid & 31;
        float sc = s_attn[g][h][kk];
        if (mval != 0) sc = -1e30f;
        float mx = sc;
        #pragma unroll
        for (int off = 16; off; off >>= 1) mx = fmaxf(mx, __shfl_xor(mx, off, 32));
        float e = __expf(sc - mx);
        float den = e;
        #pragma unroll
        for (int off = 16; off; off >>= 1) den += __shfl_xor(den, off, 32);
        s_attn[g][h][kk] = e / den;
    }
    __syncthreads();

    // ---------------- phase 4: ctx = attn @ v (from LDS V) --------------------
    {
        const int g = tid >> 7, d = tid & 127, h = d >> 5;
        float acc = 0.0f;
        #pragma unroll
        for (int kk = 0; kk < KN; ++kk)
            acc = fmaf(s_attn[g][h][kk], bf2f(u.v[g * 32 + kk][d]), acc);
        s_ctx[g][d] = acc;
    }
    __syncthreads();

    // ---------------- phase 5: out projection, x2, layernorm ------------------
    {
        const int g = tid >> 7, j = tid & 127;
        float acc2 = bo[j];
        const float4* w4 = (const float4*)(Wo + (size_t)j * HIDN);
        const float4* x4 = (const float4*)s_ctx[g];
        #pragma unroll
        for (int c = 0; c < HIDN / 4; ++c) {
            float4 wv = w4[c]; float4 x = x4[c];
            acc2 = fmaf(wv.x, x.x, acc2); acc2 = fmaf(wv.y, x.y, acc2);
            acc2 = fmaf(wv.z, x.z, acc2); acc2 = fmaf(wv.w, x.w, acc2);
        }
        float o = acc2 * 2.0f;
        float s = o, ss = o * o;
        #pragma unroll
        for (int off = 32; off; off >>= 1) {
            s  += __shfl_xor(s, off);
            ss += __shfl_xor(ss, off);
        }
        if (lane == 0) { s_red[w][0] = s; s_red[w][1] = ss; }
        __syncthreads();
        float fs  = s_red[g * 2][0] + s_red[g * 2 + 1][0];
        float fss = s_red[g * 2][1] + s_red[g * 2 + 1][1];
        float mu  = fs * (1.0f / HIDN);
        float var = fss * (1.0f / HIDN) - mu * mu;
        float y = (o - mu) * rsqrtf(var + 1e-5f) * ln_g[j] + ln_b[j];
        out[(size_t)(n0 + g) * HIDN + j] = y;
    }
}

extern "C" void kernel_launch(void* const* d_in, const int* in_sizes, int n_in,
                              void* d_out, int out_size, void* d_ws, size_t ws_size,
                              hipStream_t stream) {
    const float* src    = (const float*)d_in[0];
    const float* dest   = (const float*)d_in[1];
    const int*   adj    = (const int*)  d_in[2];
    const int*   mask   = (const int*)  d_in[3];
    const float* edges  = (const float*)d_in[4];
    const float* W_src  = (const float*)d_in[5];
    const float* b_src  = (const float*)d_in[6];
    const float* W_dest = (const float*)d_in[7];
    const float* b_dest = (const float*)d_in[8];
    const float* Wqkv   = (const float*)d_in[9];
    const float* bqkv   = (const float*)d_in[10];
    const float* Wo     = (const float*)d_in[11];
    const float* bo     = (const float*)d_in[12];
    const float* ln_g   = (const float*)d_in[13];
    const float* ln_b   = (const float*)d_in[14];
    float* outp = (float*)d_out;

    unsigned short* ws = (unsigned short*)d_ws;
    const int prep_elems = 128 * XDP + 256 * HIDN;           // 45056
    prep_weights<<<prep_elems / 256, 256, 0, stream>>>(W_src, Wqkv, ws);

    fused_gat_mfma<<<N_DEST / G, 256, 0, stream>>>(
        src, dest, adj, mask, edges, b_src, W_dest, b_dest,
        Wqkv, bqkv, Wo, bo, ln_g, ln_b,
        ws, ws + 128 * XDP, outp);
}